// Round 3
// baseline (863.901 us; speedup 1.0000x reference)
//
#include <hip/hip_runtime.h>
#include <hip/hip_bf16.h>

// MultiHeadAttention: B=4, S=1024, HIDDEN=2048, H=16, d=128, fp32 in/out.
// Pipeline: cast->bf16, QKV gemm, RoPE, V-transpose, QK^T (causal-skipped)
// -> fp32 scores in d_out, fused softmax+weights+PV (attn_pv), out proj.
// NT-GEMM template: 128x128 tile, BK=64, 256 thr, mfma_f32_16x16x32_bf16,
// global_load_lds width=16 staging.
//
// ws layout (bf16 elems), peak 117,440,512 bytes, lifetimes verified disjoint:
//   Wob  [0,          4194304)   live: cast .. gemm<3>
//   xb   [4194304,   12582912)   live: cast .. gemm<0>
//   Wqkv [12582912,  25165824)   live: cast .. gemm<0>
//   QKV  [25165824,  50331648)   live: gemm<0> .. gemm<1> (V until transpose)
//   Vt   [50331648,  58720256)   live: transpose .. attn_pv
//   AO   [4194304,   12582912)   overlays dead xb; live: attn_pv .. gemm<3>

typedef __attribute__((ext_vector_type(8))) short bf16x8;
typedef __attribute__((ext_vector_type(4))) float f32x4;

#define GLD_LDS16(g, l)                                                      \
  __builtin_amdgcn_global_load_lds(                                          \
      (const __attribute__((address_space(1))) unsigned int*)(g),            \
      (__attribute__((address_space(3))) unsigned int*)(l), 16, 0, 0)

// ---------------------------------------------------------------- cast fp32->bf16
__global__ __launch_bounds__(256) void cast_kernel(
    const float* __restrict__ in, __hip_bfloat16* __restrict__ out, int n8) {
  int idx = blockIdx.x * 256 + threadIdx.x;
  if (idx >= n8) return;
  const float4* p = (const float4*)in;
  float4 a = p[idx * 2], b = p[idx * 2 + 1];
  __hip_bfloat16 h[8] = {__float2bfloat16(a.x), __float2bfloat16(a.y),
                         __float2bfloat16(a.z), __float2bfloat16(a.w),
                         __float2bfloat16(b.x), __float2bfloat16(b.y),
                         __float2bfloat16(b.z), __float2bfloat16(b.w)};
  uint4 u;
  __builtin_memcpy(&u, h, 16);
  ((uint4*)out)[idx] = u;
}

// ---------------------------------------------------------------- NT GEMM
// C[m,n] = scale * sum_k A[m,k] * B[n,k]
// MODE 0: QKV proj, z in {0,1,2}. M=4096 N=2048 K=2048, bf16 out
// MODE 1: scores, z=b*16+h. M=N=1024 K=128, fp32 out (*1/sqrt(128)), causal skip
// MODE 3: out proj. M=4096 N=2048 K=2048, fp32 out
template <int MODE>
__global__ __launch_bounds__(256) void gemm_nt(
    const __hip_bfloat16* __restrict__ Abase,
    const __hip_bfloat16* __restrict__ Bbase, void* __restrict__ Cbase) {
  __shared__ alignas(16) __hip_bfloat16 lA[128][64];
  __shared__ alignas(16) __hip_bfloat16 lB[128][64];

  const int tid = threadIdx.x;
  const int m0 = blockIdx.y * 128;
  const int n0 = blockIdx.x * 128;
  const int z = blockIdx.z;

  const __hip_bfloat16* A;
  const __hip_bfloat16* Bm;
  int lda = 2048, ldb = 2048, K = 2048;
  if constexpr (MODE == 0) {
    A = Abase;
    Bm = Bbase + (size_t)z * (2048 * 2048);
  } else if constexpr (MODE == 1) {
    if (n0 > m0) return;  // tile fully above causal diagonal
    int b = z >> 4, h = z & 15;
    A = Abase + ((size_t)b * 1024) * 2048 + h * 128;
    Bm = Bbase + ((size_t)b * 1024) * 2048 + h * 128;
    K = 128;
  } else {
    A = Abase;
    Bm = Bbase;
  }

  const int lane = tid & 63;
  const int wid = tid >> 6;
  const int wm = (wid & 1) * 64;
  const int wn = (wid >> 1) * 64;
  const int frow = lane & 15;
  const int fk = (lane >> 4) * 8;

  f32x4 acc[4][4] = {};

  for (int k0 = 0; k0 < K; k0 += 64) {
    __syncthreads();
#pragma unroll
    for (int c = 0; c < 4; ++c) {
      int lin = c * 256 + tid;
      int r = lin >> 3;
      int col = (lin & 7) << 3;
      GLD_LDS16(A + (size_t)(m0 + r) * lda + k0 + col, &lA[r][col]);
    }
#pragma unroll
    for (int c = 0; c < 4; ++c) {
      int lin = c * 256 + tid;
      int r = lin >> 3;
      int col = (lin & 7) << 3;
      GLD_LDS16(Bm + (size_t)(n0 + r) * ldb + k0 + col, &lB[r][col]);
    }
    __syncthreads();
#pragma unroll
    for (int kk = 0; kk < 64; kk += 32) {
      bf16x8 av[4], bv[4];
#pragma unroll
      for (int i = 0; i < 4; ++i)
        av[i] = *(const bf16x8*)&lA[wm + i * 16 + frow][kk + fk];
#pragma unroll
      for (int i = 0; i < 4; ++i)
        bv[i] = *(const bf16x8*)&lB[wn + i * 16 + frow][kk + fk];
#pragma unroll
      for (int mi = 0; mi < 4; ++mi)
#pragma unroll
        for (int ni = 0; ni < 4; ++ni)
          acc[mi][ni] = __builtin_amdgcn_mfma_f32_16x16x32_bf16(
              av[mi], bv[ni], acc[mi][ni], 0, 0, 0);
    }
  }

  // C/D layout: col = lane&15, row = (lane>>4)*4 + reg
  const int r0 = (lane >> 4) * 4;
  const int cc = lane & 15;

  if constexpr (MODE == 1) {
    float* C = (float*)Cbase + (size_t)z * (1024 * 1024);
    const float scale = 0.08838834764831845f;  // 1/sqrt(128)
#pragma unroll
    for (int mi = 0; mi < 4; ++mi)
#pragma unroll
      for (int ni = 0; ni < 4; ++ni)
#pragma unroll
        for (int r = 0; r < 4; ++r)
          C[(size_t)(m0 + wm + mi * 16 + r0 + r) * 1024 +
            (n0 + wn + ni * 16 + cc)] = acc[mi][ni][r] * scale;
  } else if constexpr (MODE == 3) {
    float* C = (float*)Cbase;
#pragma unroll
    for (int mi = 0; mi < 4; ++mi)
#pragma unroll
      for (int ni = 0; ni < 4; ++ni)
#pragma unroll
        for (int r = 0; r < 4; ++r)
          C[(size_t)(m0 + wm + mi * 16 + r0 + r) * 2048 +
            (n0 + wn + ni * 16 + cc)] = acc[mi][ni][r];
  } else {  // MODE 0, bf16 out
    __hip_bfloat16* C = (__hip_bfloat16*)Cbase + (size_t)z * (4096 * 2048);
#pragma unroll
    for (int mi = 0; mi < 4; ++mi)
#pragma unroll
      for (int ni = 0; ni < 4; ++ni)
#pragma unroll
        for (int r = 0; r < 4; ++r)
          C[(size_t)(m0 + wm + mi * 16 + r0 + r) * 2048 +
            (n0 + wn + ni * 16 + cc)] = __float2bfloat16(acc[mi][ni][r]);
  }
}

// ---------------------------------------------------------------- RoPE (in place, Llama half-split)
__global__ __launch_bounds__(256) void rope_kernel(__hip_bfloat16* __restrict__ Qb,
                                                   __hip_bfloat16* __restrict__ Kb) {
  __hip_bfloat16* p = blockIdx.y ? Kb : Qb;
  int idx = blockIdx.x * 256 + threadIdx.x;  // 0 .. 4*1024*16*64-1
  int j = idx & 63;
  int h = (idx >> 6) & 15;
  int spos = (idx >> 10) & 1023;
  int b = idx >> 20;
  float inv_freq = __expf(-((float)(2 * j) / 128.f) * 9.210340371976184f);
  float ang = (float)spos * inv_freq;
  float c = cosf(ang), sn = sinf(ang);
  size_t base = ((size_t)(b * 1024 + spos)) * 2048 + h * 128 + j;
  float x1 = __bfloat162float(p[base]);
  float x2 = __bfloat162float(p[base + 64]);
  p[base] = __float2bfloat16(x1 * c - x2 * sn);
  p[base + 64] = __float2bfloat16(x2 * c + x1 * sn);
}

// ---------------------------------------------------------------- V transpose [b,s,h,d] -> [b,h,d,s]
__global__ __launch_bounds__(256) void transpose_v(
    const __hip_bfloat16* __restrict__ Vb, __hip_bfloat16* __restrict__ Vt) {
  __shared__ __hip_bfloat16 t[64][65];
  int s0 = blockIdx.x * 64;
  int j0 = blockIdx.y * 64;
  int bh = blockIdx.z;
  int b = bh >> 4, h = bh & 15;
  const __hip_bfloat16* src = Vb + ((size_t)b * 1024) * 2048 + h * 128;
#pragma unroll
  for (int it = 0; it < 16; ++it) {
    int lin = it * 256 + threadIdx.x;
    int r = lin >> 6, c = lin & 63;
    t[r][c] = src[(size_t)(s0 + r) * 2048 + j0 + c];
  }
  __syncthreads();
  __hip_bfloat16* dst = Vt + ((size_t)bh * 128 + j0) * 1024 + s0;
#pragma unroll
  for (int it = 0; it < 16; ++it) {
    int lin = it * 256 + threadIdx.x;
    int r = lin >> 6, c = lin & 63;
    dst[(size_t)r * 1024 + c] = t[c][r];
  }
}

// ---------------------------------------------------------------- fused softmax + weights + PV
// One block = 128 query rows of one (b,h). Sweep 1: online row max/sum over
// fp32 scores (L2-hot, written by gemm<1>). Sweep 2 per 128-key tile: stage
// Vt tile via global_load_lds, normalize scores -> fp32 weights to d_out +
// bf16 P to LDS, MFMA O += P*V. Epilogue: zero upper triangle, bf16 O via
// LDS bounce to AO.
__global__ __launch_bounds__(256) void attn_pv(
    float* __restrict__ scores, const float* __restrict__ mask,
    const __hip_bfloat16* __restrict__ Vt, __hip_bfloat16* __restrict__ AO) {
  __shared__ alignas(16) __hip_bfloat16 lV[128][128];  // [d][k] tile
  __shared__ alignas(16) __hip_bfloat16 lP[128][128];  // [row][k]; reused for O
  __shared__ float sm[128], si[128];

  const int tid = threadIdx.x;
  const int lane = tid & 63;
  const int wid = tid >> 6;
  const int mb = blockIdx.x;
  const int m0 = mb * 128;
  const int z = blockIdx.y;
  const int b = z >> 4, h = z & 15;

  float* S = scores + (size_t)z * (1024 * 1024);
  const float* mrow = mask + b * 1024;

  // ---- sweep 1: per-row online max/sum (rows wid*32 .. wid*32+31)
  const int half = lane >> 5;       // 0/1: which of the two rows per iter
  const int csub = lane & 31;       // 32 lanes cover 128 cols as float4
  for (int rr = 0; rr < 32; rr += 2) {
    int r = wid * 32 + rr + half;
    int i = m0 + r;
    float m_run = -3.0e38f, s_run = 0.f;
    for (int kt = 0; kt <= mb; ++kt) {
      int jj = kt * 128 + csub * 4;
      float4 s4 = *(const float4*)&S[(size_t)(m0 + r) * 1024 + jj];
      float4 k4 = *(const float4*)&mrow[jj];
      float v0 = (jj + 0 <= i) ? s4.x + k4.x : -3.0e38f;
      float v1 = (jj + 1 <= i) ? s4.y + k4.y : -3.0e38f;
      float v2 = (jj + 2 <= i) ? s4.z + k4.z : -3.0e38f;
      float v3 = (jj + 3 <= i) ? s4.w + k4.w : -3.0e38f;
      float tmx = fmaxf(fmaxf(v0, v1), fmaxf(v2, v3));
      float mn = fmaxf(m_run, tmx);
      s_run = s_run * __expf(m_run - mn);
      s_run += (jj + 0 <= i ? __expf(v0 - mn) : 0.f) +
               (jj + 1 <= i ? __expf(v1 - mn) : 0.f) +
               (jj + 2 <= i ? __expf(v2 - mn) : 0.f) +
               (jj + 3 <= i ? __expf(v3 - mn) : 0.f);
      m_run = mn;
    }
    // reduce (m,s) across the 32 lanes of this half
#pragma unroll
    for (int off = 1; off < 32; off <<= 1) {
      float mo = __shfl_xor(m_run, off, 64);
      float so = __shfl_xor(s_run, off, 64);
      float mn = fmaxf(m_run, mo);
      s_run = s_run * __expf(m_run - mn) + so * __expf(mo - mn);
      m_run = mn;
    }
    if (csub == 0) {
      sm[r] = m_run;
      si[r] = 1.0f / s_run;
    }
  }

  // ---- sweep 2: per key-tile normalize + write weights + PV accumulate
  const int wm = (wid & 1) * 64;
  const int wn = (wid >> 1) * 64;
  const int frow = lane & 15;
  const int fk = (lane >> 4) * 8;
  f32x4 oacc[4][4] = {};

  for (int kt = 0; kt <= mb; ++kt) {
    const int c0 = kt * 128;
    __syncthreads();  // prev-iter MFMA reads done; sweep-1 done (first iter)
    // stage Vt tile [d=128][k=128]
#pragma unroll
    for (int it = 0; it < 8; ++it) {
      int lin = it * 256 + tid;
      int r = lin >> 4;
      int c = (lin & 15) << 3;
      GLD_LDS16(Vt + ((size_t)z * 128 + r) * 1024 + c0 + c, &lV[r][c]);
    }
    // normalize 128x128 score tile; rows wid*32..+31
    for (int rr = 0; rr < 32; rr += 2) {
      int r = wid * 32 + rr + half;
      int i = m0 + r;
      int jj = c0 + csub * 4;
      float m_r = sm[r], iv = si[r];
      float4 s4 = *(const float4*)&S[(size_t)(m0 + r) * 1024 + jj];
      float4 k4 = *(const float4*)&mrow[jj];
      float p0 = (jj + 0 <= i) ? __expf(s4.x + k4.x - m_r) * iv : 0.f;
      float p1 = (jj + 1 <= i) ? __expf(s4.y + k4.y - m_r) * iv : 0.f;
      float p2 = (jj + 2 <= i) ? __expf(s4.z + k4.z - m_r) * iv : 0.f;
      float p3 = (jj + 3 <= i) ? __expf(s4.w + k4.w - m_r) * iv : 0.f;
      *(float4*)&S[(size_t)(m0 + r) * 1024 + jj] = make_float4(p0, p1, p2, p3);
      __hip_bfloat16 hb[4] = {__float2bfloat16(p0), __float2bfloat16(p1),
                              __float2bfloat16(p2), __float2bfloat16(p3)};
      unsigned long long u;
      __builtin_memcpy(&u, hb, 8);
      *(unsigned long long*)&lP[r][csub * 4] = u;
    }
    __syncthreads();  // lV staged (vmcnt drained at barrier) + lP written
#pragma unroll
    for (int ks = 0; ks < 4; ++ks) {
      bf16x8 av[4], bv[4];
#pragma unroll
      for (int mi = 0; mi < 4; ++mi)
        av[mi] = *(const bf16x8*)&lP[wm + mi * 16 + frow][ks * 32 + fk];
#pragma unroll
      for (int ni = 0; ni < 4; ++ni)
        bv[ni] = *(const bf16x8*)&lV[wn + ni * 16 + frow][ks * 32 + fk];
#pragma unroll
      for (int mi = 0; mi < 4; ++mi)
#pragma unroll
        for (int ni = 0; ni < 4; ++ni)
          oacc[mi][ni] = __builtin_amdgcn_mfma_f32_16x16x32_bf16(
              av[mi], bv[ni], oacc[mi][ni], 0, 0, 0);
    }
  }

  // ---- zero-fill weights cols [m0+128, 1024) for these 128 rows
  {
    const float4 z4 = make_float4(0.f, 0.f, 0.f, 0.f);
    for (int r = 0; r < 128; ++r) {
      for (int j = m0 + 128 + tid * 4; j < 1024; j += 1024)
        *(float4*)&S[(size_t)(m0 + r) * 1024 + j] = z4;
    }
  }

  // ---- epilogue: O (C-layout regs) -> LDS bounce -> coalesced bf16 stores
  __syncthreads();  // all MFMA reads of lP done
  const int r0 = (lane >> 4) * 4;
  const int cc = lane & 15;
#pragma unroll
  for (int mi = 0; mi < 4; ++mi)
#pragma unroll
    for (int ni = 0; ni < 4; ++ni)
#pragma unroll
      for (int r = 0; r < 4; ++r)
        lP[wm + mi * 16 + r0 + r][wn + ni * 16 + cc] =
            __float2bfloat16(oacc[mi][ni][r]);
  __syncthreads();
#pragma unroll
  for (int it = 0; it < 8; ++it) {
    int lin = it * 256 + tid;
    int r = lin >> 4;
    int c = (lin & 15) << 3;
    *(uint4*)&AO[((size_t)(b * 1024) + m0 + r) * 2048 + h * 128 + c] =
        *(const uint4*)&lP[r][c];
  }
}

// ---------------------------------------------------------------- launch
extern "C" void kernel_launch(void* const* d_in, const int* in_sizes, int n_in,
                              void* d_out, int out_size, void* d_ws,
                              size_t ws_size, hipStream_t stream) {
  const float* x = (const float*)d_in[0];
  const float* mask = (const float*)d_in[1];
  const float* Wq = (const float*)d_in[2];
  const float* Wk = (const float*)d_in[3];
  const float* Wv = (const float*)d_in[4];
  const float* Wo = (const float*)d_in[5];
  float* out = (float*)d_out;
  float* attnw = out + (size_t)4 * 1024 * 2048;  // fp32 weights region of d_out

  __hip_bfloat16* wsb = (__hip_bfloat16*)d_ws;
  __hip_bfloat16* Wob = wsb;                 //  4,194,304
  __hip_bfloat16* xb  = wsb + 4194304;       //  8,388,608
  __hip_bfloat16* Wqb = wsb + 12582912;      //  3x 4,194,304 (Wq,Wk,Wv contig)
  __hip_bfloat16* Qb  = wsb + 25165824;      //  3x 8,388,608 (Q,K,V contig)
  __hip_bfloat16* Kb  = wsb + 33554432;
  __hip_bfloat16* Vb  = wsb + 41943040;
  __hip_bfloat16* Vt  = wsb + 50331648;      //  8,388,608
  __hip_bfloat16* AO  = wsb + 4194304;       //  8,388,608 (overlays dead xb)

  cast_kernel<<<4096, 256, 0, stream>>>(x, xb, 1048576);
  cast_kernel<<<2048, 256, 0, stream>>>(Wq, Wqb, 524288);
  cast_kernel<<<2048, 256, 0, stream>>>(Wk, Wqb + 4194304, 524288);
  cast_kernel<<<2048, 256, 0, stream>>>(Wv, Wqb + 8388608, 524288);
  cast_kernel<<<2048, 256, 0, stream>>>(Wo, Wob, 524288);

  gemm_nt<0><<<dim3(16, 32, 3), 256, 0, stream>>>(xb, Wqb, Qb);
  rope_kernel<<<dim3(16384, 2), 256, 0, stream>>>(Qb, Kb);
  transpose_v<<<dim3(16, 2, 64), 256, 0, stream>>>(Vb, Vt);
  gemm_nt<1><<<dim3(8, 8, 64), 256, 0, stream>>>(Qb, Kb, attnw);
  attn_pv<<<dim3(8, 64), 256, 0, stream>>>(attnw, mask, Vt, AO);
  gemm_nt<3><<<dim3(16, 32, 1), 256, 0, stream>>>(AO, Wob, out);
}